// Round 1
// baseline (286.938 us; speedup 1.0000x reference)
//
#include <hip/hip_runtime.h>
#include <cstdint>
#include <cstddef>

typedef unsigned short u16;
typedef __attribute__((ext_vector_type(8))) short short8;
typedef __attribute__((ext_vector_type(4))) float f32x4;

#define BB 4
#define SS 2048
#define DD 1024

__device__ __forceinline__ u16 f2bf(float f) {
  union { float f; unsigned u; } x; x.f = f;
  unsigned r = x.u + 0x7FFFu + ((x.u >> 16) & 1u);
  return (u16)(r >> 16);
}

__device__ __forceinline__ void gld_lds16(const void* g, void* l) {
  __builtin_amdgcn_global_load_lds(
      (const __attribute__((address_space(1))) void*)g,
      (__attribute__((address_space(3))) void*)l, 16, 0, 0);
}

__device__ __forceinline__ void store_out(float* p, float v) { *p = v; }
__device__ __forceinline__ void store_out(u16* p, float v) { *p = f2bf(v); }

// C = A * B^T-layout (+bias) * scale.
// A: [M][K] bf16 row-major (lda), B: [N][K] bf16 row-major (ldb).
// 128x128 tile, BK=32, 4 waves, global_load_lds staging (m97 structure).
template<typename OutT, bool TRANS_OUT, bool HAS_BIAS>
__global__ __launch_bounds__(256) void gemm_bt(
    const u16* __restrict__ A, size_t sA, int lda,
    const u16* __restrict__ B, size_t sB, int ldb,
    OutT* __restrict__ C, size_t sC, int ldc,
    const float* __restrict__ bias, float scale, int K)
{
  __shared__ u16 smA[128 * 32];
  __shared__ u16 smB[128 * 32];

  A += (size_t)blockIdx.z * sA;
  B += (size_t)blockIdx.z * sB;
  C += (size_t)blockIdx.z * sC;

  const int tid  = threadIdx.x;
  const int wave = tid >> 6;
  const int lane = tid & 63;
  const int blockM = blockIdx.y * 128;
  const int blockN = blockIdx.x * 128;
  const int wrow = (wave >> 1) * 64;
  const int wcol = (wave & 1) * 64;

  f32x4 acc[4][4] = {};

  const int crow = lane >> 2;        // 0..15 row within 16-row chunk
  const int ck8  = (lane & 3) * 8;   // k element offset (8 bf16 = 16B)

  for (int kt = 0; kt < K; kt += 32) {
    // ---- stage A (chunks 0..7) and B (chunks 8..15); wave w owns 4w..4w+3
#pragma unroll
    for (int i = 0; i < 4; ++i) {
      int c = wave * 4 + i;
      if (c < 8) {
        const u16* g = A + (size_t)(blockM + c * 16 + crow) * lda + kt + ck8;
        gld_lds16(g, smA + c * 512);
      } else {
        int c2 = c - 8;
        const u16* g = B + (size_t)(blockN + c2 * 16 + crow) * ldb + kt + ck8;
        gld_lds16(g, smB + c2 * 512);
      }
    }
    __syncthreads();

    // ---- fragments + 16 MFMA
    const int r  = lane & 15;
    const int s8 = (lane >> 4) * 8;
    short8 af[4], bfr[4];
#pragma unroll
    for (int mi = 0; mi < 4; ++mi)
      af[mi] = *(const short8*)(smA + (wrow + mi * 16 + r) * 32 + s8);
#pragma unroll
    for (int ni = 0; ni < 4; ++ni)
      bfr[ni] = *(const short8*)(smB + (wcol + ni * 16 + r) * 32 + s8);
#pragma unroll
    for (int mi = 0; mi < 4; ++mi)
#pragma unroll
      for (int ni = 0; ni < 4; ++ni)
        acc[mi][ni] = __builtin_amdgcn_mfma_f32_16x16x32_bf16(
            af[mi], bfr[ni], acc[mi][ni], 0, 0, 0);
    __syncthreads();
  }

  // ---- epilogue: C/D layout col=lane&15, row=(lane>>4)*4+i
  const int cr = lane & 15;
  const int rr = (lane >> 4) * 4;
#pragma unroll
  for (int ni = 0; ni < 4; ++ni) {
    int colg = blockN + wcol + ni * 16 + cr;
    float bval = HAS_BIAS ? bias[colg] : 0.0f;
#pragma unroll
    for (int mi = 0; mi < 4; ++mi) {
      f32x4 v = acc[mi][ni];
      int rowg = blockM + wrow + mi * 16 + rr;
      if constexpr (TRANS_OUT) {
        // write C^T: 4 consecutive rows at fixed col -> 8B packed store
        u16 h0 = f2bf(v[0] * scale + bval);
        u16 h1 = f2bf(v[1] * scale + bval);
        u16 h2 = f2bf(v[2] * scale + bval);
        u16 h3 = f2bf(v[3] * scale + bval);
        uint2 u;
        u.x = (unsigned)h0 | ((unsigned)h1 << 16);
        u.y = (unsigned)h2 | ((unsigned)h3 << 16);
        *(uint2*)&C[(size_t)colg * ldc + rowg] = u;
      } else {
#pragma unroll
        for (int i = 0; i < 4; ++i) {
          store_out(&C[(size_t)(rowg + i) * ldc + colg], v[i] * scale + bval);
        }
      }
    }
  }
}

// fp32 -> bf16 elementwise, float4-vectorized (n4 = n/4 float4s)
__global__ __launch_bounds__(256) void cvt_f32_bf16(
    const float* __restrict__ in, u16* __restrict__ out, int n4)
{
  int i = blockIdx.x * 256 + threadIdx.x;
  if (i >= n4) return;
  float4 v = ((const float4*)in)[i];
  uint2 u;
  u.x = (unsigned)f2bf(v.x) | ((unsigned)f2bf(v.y) << 16);
  u.y = (unsigned)f2bf(v.z) | ((unsigned)f2bf(v.w) << 16);
  ((uint2*)out)[i] = u;
}

// W [1024][1024] f32 -> Wt [1024][1024] bf16, Wt[f][d] = W[d][f]
__global__ __launch_bounds__(256) void transpose_cvt(
    const float* __restrict__ W, u16* __restrict__ Wt)
{
  __shared__ u16 tile[32][33];
  const int tx = threadIdx.x;   // 0..31
  const int ty = threadIdx.y;   // 0..7
  const int bx = blockIdx.x * 32;  // f base
  const int by = blockIdx.y * 32;  // d base
#pragma unroll
  for (int j = 0; j < 4; ++j) {
    int d = by + ty * 4 + j;
    tile[ty * 4 + j][tx] = f2bf(W[(size_t)d * DD + bx + tx]);
  }
  __syncthreads();
#pragma unroll
  for (int j = 0; j < 4; ++j) {
    int f = bx + ty * 4 + j;
    Wt[(size_t)f * DD + by + tx] = tile[tx][ty * 4 + j];
  }
}

// in-place row softmax: read 2048 fp32, write 2048 bf16 over same memory.
__global__ __launch_bounds__(256) void softmax_inplace(float* __restrict__ S)
{
  const int tid = threadIdx.x;
  float* rp = S + (size_t)blockIdx.x * SS;

  float4 v0 = ((const float4*)rp)[tid];
  float4 v1 = ((const float4*)rp)[tid + 256];

  float m = fmaxf(fmaxf(fmaxf(v0.x, v0.y), fmaxf(v0.z, v0.w)),
                  fmaxf(fmaxf(v1.x, v1.y), fmaxf(v1.z, v1.w)));
#pragma unroll
  for (int off = 32; off; off >>= 1) m = fmaxf(m, __shfl_xor(m, off));

  __shared__ float smax[4];
  __shared__ float ssum[4];
  const int wave = tid >> 6, lane = tid & 63;
  if (lane == 0) smax[wave] = m;
  __syncthreads();
  m = fmaxf(fmaxf(smax[0], smax[1]), fmaxf(smax[2], smax[3]));

  float e[8];
  e[0] = __expf(v0.x - m); e[1] = __expf(v0.y - m);
  e[2] = __expf(v0.z - m); e[3] = __expf(v0.w - m);
  e[4] = __expf(v1.x - m); e[5] = __expf(v1.y - m);
  e[6] = __expf(v1.z - m); e[7] = __expf(v1.w - m);
  float s = e[0] + e[1] + e[2] + e[3] + e[4] + e[5] + e[6] + e[7];
#pragma unroll
  for (int off = 32; off; off >>= 1) s += __shfl_xor(s, off);
  if (lane == 0) ssum[wave] = s;
  __syncthreads();
  float inv = 1.0f / (ssum[0] + ssum[1] + ssum[2] + ssum[3]);

  uint2 u0, u1;
  u0.x = (unsigned)f2bf(e[0] * inv) | ((unsigned)f2bf(e[1] * inv) << 16);
  u0.y = (unsigned)f2bf(e[2] * inv) | ((unsigned)f2bf(e[3] * inv) << 16);
  u1.x = (unsigned)f2bf(e[4] * inv) | ((unsigned)f2bf(e[5] * inv) << 16);
  u1.y = (unsigned)f2bf(e[6] * inv) | ((unsigned)f2bf(e[7] * inv) << 16);
  ((uint2*)rp)[tid]       = u0;   // bf16 elems 4t..4t+3
  ((uint2*)rp)[tid + 256] = u1;   // bf16 elems 1024+4t..
}

extern "C" void kernel_launch(void* const* d_in, const int* in_sizes, int n_in,
                              void* d_out, int out_size, void* d_ws, size_t ws_size,
                              hipStream_t stream) {
  (void)in_sizes; (void)n_in; (void)out_size; (void)ws_size;
  const float* X  = (const float*)d_in[0];
  const float* Wq = (const float*)d_in[1];
  const float* bq = (const float*)d_in[2];
  const float* Wk = (const float*)d_in[3];
  const float* bk = (const float*)d_in[4];
  const float* Wv = (const float*)d_in[5];
  const float* bv = (const float*)d_in[6];
  const float* Wo = (const float*)d_in[7];
  const float* bo = (const float*)d_in[8];

  char* ws = (char*)d_ws;
  const size_t MBy = 1ull << 20;
  u16*  Xbf = (u16*)(ws + 0);          // 16 MB  [8192][1024]
  u16*  Wtq = (u16*)(ws + 16 * MBy);   //  2 MB  [1024][1024] (f,d)
  u16*  Wtk = (u16*)(ws + 18 * MBy);
  u16*  Wtv = (u16*)(ws + 20 * MBy);
  u16*  Wto = (u16*)(ws + 22 * MBy);
  u16*  Qb  = (u16*)(ws + 24 * MBy);   // 16 MB  [8192][1024]
  u16*  Kb  = (u16*)(ws + 40 * MBy);   // 16 MB
  u16*  Vt  = (u16*)(ws + 56 * MBy);   // 16 MB  [4][1024][2048] (b,d,t)
  float* Sf = (float*)(ws + 72 * MBy); // 64 MB  [4][2048][2048]; P bf16 in-place
  u16*  Ctx = (u16*)(ws + 136 * MBy);  // 16 MB  [8192][1024]

  // 1. conversions
  cvt_f32_bf16<<<dim3((BB * SS * DD / 4) / 256), 256, 0, stream>>>(X, Xbf, BB * SS * DD / 4);
  dim3 tb(32, 8);
  transpose_cvt<<<dim3(32, 32), tb, 0, stream>>>(Wq, Wtq);
  transpose_cvt<<<dim3(32, 32), tb, 0, stream>>>(Wk, Wtk);
  transpose_cvt<<<dim3(32, 32), tb, 0, stream>>>(Wv, Wtv);
  transpose_cvt<<<dim3(32, 32), tb, 0, stream>>>(Wo, Wto);

  // 2. Q, K projections: [8192][1024] = Xbf * Wt^T
  gemm_bt<u16, false, true><<<dim3(8, 64, 1), 256, 0, stream>>>(
      Xbf, 0, DD, Wtq, 0, DD, Qb, 0, DD, bq, 1.0f, DD);
  gemm_bt<u16, false, true><<<dim3(8, 64, 1), 256, 0, stream>>>(
      Xbf, 0, DD, Wtk, 0, DD, Kb, 0, DD, bk, 1.0f, DD);
  // V projection, written transposed per batch: Vt[b][d][t]
  gemm_bt<u16, true, true><<<dim3(8, 16, BB), 256, 0, stream>>>(
      Xbf, (size_t)SS * DD, DD, Wtv, 0, DD, Vt, (size_t)DD * SS, SS, bv, 1.0f, DD);

  // 3. scores = Q K^T / 8  (fp32)
  gemm_bt<float, false, false><<<dim3(16, 16, BB), 256, 0, stream>>>(
      Qb, (size_t)SS * DD, DD, Kb, (size_t)SS * DD, DD,
      Sf, (size_t)SS * SS, SS, nullptr, 0.125f, DD);

  // 4. softmax rows (in-place fp32 -> bf16)
  softmax_inplace<<<dim3(BB * SS), 256, 0, stream>>>(Sf);

  // 5. ctx = P V   (P: bf16 in Sf, lda = 2*SS; B-operand = Vt [d][t])
  gemm_bt<u16, false, false><<<dim3(8, 16, BB), 256, 0, stream>>>(
      (const u16*)Sf, (size_t)SS * 2 * SS, 2 * SS,
      Vt, (size_t)DD * SS, SS,
      Ctx, (size_t)SS * DD, DD, nullptr, 1.0f, SS);

  // 6. out = ctx Wo^T + bo (fp32)
  gemm_bt<float, false, true><<<dim3(8, 64, 1), 256, 0, stream>>>(
      Ctx, 0, DD, Wto, 0, DD, (float*)d_out, 0, DD, bo, 1.0f, DD);
}

// Round 2
// 250.206 us; speedup vs baseline: 1.1468x; 1.1468x over previous
//
#include <hip/hip_runtime.h>
#include <cstdint>
#include <cstddef>

typedef unsigned short u16;
typedef __attribute__((ext_vector_type(8))) short short8;
typedef __attribute__((ext_vector_type(4))) float f32x4;

#define BB 4
#define SS 2048
#define DD 1024

__device__ __forceinline__ u16 f2bf(float f) {
  union { float f; unsigned u; } x; x.f = f;
  unsigned r = x.u + 0x7FFFu + ((x.u >> 16) & 1u);
  return (u16)(r >> 16);
}

__device__ __forceinline__ void gld_lds16(const void* g, void* l) {
  __builtin_amdgcn_global_load_lds(
      (const __attribute__((address_space(1))) void*)g,
      (__attribute__((address_space(3))) void*)l, 16, 0, 0);
}

__device__ __forceinline__ void store_out(float* p, float v) { *p = v; }
__device__ __forceinline__ void store_out(u16* p, float v) { *p = f2bf(v); }

// ---------------------------------------------------------------------------
// 256x256-tile, BK=32, 8-wave GEMM with triple-buffered LDS, counted vmcnt,
// XOR-swizzled LDS, XCD-aware block swizzle, setprio around MFMA cluster.
// A: [M][K] bf16 (ldaB bytes/row), B: [N][K] bf16 (ldbB bytes/row).
// MODE 0: C[row][col] (OutT) = acc*scale (+bias[col]).
// MODE 1: QKV split: cols 0-1023 -> C (Q), 1024-2047 -> out2 (K),
//         2048-3071 -> out3 transposed Vt[b][d][t]  (all bf16, +bias).
// Grid: x = N/256, y = M/256, z = batch. nwg must be divisible by 8.
// ---------------------------------------------------------------------------
template<typename OutT, int MODE, bool HAS_BIAS>
__global__ __launch_bounds__(512, 2) void gemm8(
    const u16* __restrict__ A, size_t sA, int ldaB,
    const u16* __restrict__ B, size_t sB, int ldbB,
    OutT* __restrict__ C, size_t sC, int ldc,
    const float* __restrict__ bias, float scale, int K,
    u16* __restrict__ out2, u16* __restrict__ out3)
{
  __shared__ u16 sm[3 * 16384];   // 3 bufs x (A 256x32 + B 256x32) = 96 KB

  // ---- XCD-aware block swizzle (bijective: all grids % 8 == 0)
  const int gx = gridDim.x, gy = gridDim.y;
  const int nwg = gx * gy * gridDim.z;
  const int flat = blockIdx.x + gx * (blockIdx.y + gy * blockIdx.z);
  const int swz = (flat & 7) * (nwg >> 3) + (flat >> 3);
  const int bz = swz / (gx * gy);
  const int rem = swz - bz * (gx * gy);
  const int by = rem / gx;
  const int bx = rem - by * gx;
  const int blockM = by * 256, blockN = bx * 256;

  const char* Ab = (const char*)(A + (size_t)bz * sA);
  const char* Bb = (const char*)(B + (size_t)bz * sB);

  const int tid  = threadIdx.x;
  const int wave = tid >> 6, lane = tid & 63;
  const int wrow = (wave >> 2) * 128;   // wm*128
  const int wcol = (wave & 3) * 64;     // wn*64

  // ---- staging source addressing (pre-swizzled global: cb ^= (row&3)<<4)
  const int rowS = tid >> 2;                               // 0..127
  const int cbS  = ((tid & 3) * 16) ^ ((rowS & 3) << 4);   // bytes within row
  const char* gA0 = Ab + (size_t)(blockM + rowS) * ldaB + cbS;
  const char* gA1 = gA0 + (size_t)128 * ldaB;
  const char* gB0 = Bb + (size_t)(blockN + rowS) * ldbB + cbS;
  const char* gB1 = gB0 + (size_t)128 * ldbB;
  const int dA0 = wave * 512;  // wave-uniform LDS dest base (elems)

  // ---- fragment read addressing (swizzled)
  const int r = lane & 15, q = lane >> 4;
  const int rA = wrow + r;
  const int rB = wcol + r;
  const int eA = rA * 32 + ((((q * 16) ^ ((rA & 3) << 4))) >> 1);
  const int eB = rB * 32 + ((((q * 16) ^ ((rB & 3) << 4))) >> 1);

  f32x4 acc[8][4] = {};

  u16* rd = sm;            // buffer t%3
  u16* nx = sm + 16384;
  u16* st = sm + 32768;    // buffer (t+2)%3 (stage target)

  const int NT = K >> 5;

  // ---- prologue: stage tiles 0 and 1
  gld_lds16(gA0, rd + dA0);          gld_lds16(gA1, rd + 4096 + dA0);
  gld_lds16(gB0, rd + 8192 + dA0);   gld_lds16(gB1, rd + 12288 + dA0);
  gA0 += 64; gA1 += 64; gB0 += 64; gB1 += 64;
  gld_lds16(gA0, nx + dA0);          gld_lds16(gA1, nx + 4096 + dA0);
  gld_lds16(gB0, nx + 8192 + dA0);   gld_lds16(gB1, nx + 12288 + dA0);
  gA0 += 64; gA1 += 64; gB0 += 64; gB1 += 64;

  for (int t = 0; t < NT; ++t) {
    if (t < NT - 1) { asm volatile("s_waitcnt vmcnt(4)" ::: "memory"); }
    else            { asm volatile("s_waitcnt vmcnt(0)" ::: "memory"); }
    __builtin_amdgcn_s_barrier();

    if (t + 2 < NT) {
      gld_lds16(gA0, st + dA0);          gld_lds16(gA1, st + 4096 + dA0);
      gld_lds16(gB0, st + 8192 + dA0);   gld_lds16(gB1, st + 12288 + dA0);
      gA0 += 64; gA1 += 64; gB0 += 64; gB1 += 64;
    }

    short8 af[8], bfr[4];
#pragma unroll
    for (int i = 0; i < 8; ++i)
      af[i] = *(const short8*)(rd + eA + i * 512);
#pragma unroll
    for (int j = 0; j < 4; ++j)
      bfr[j] = *(const short8*)(rd + 8192 + eB + j * 512);

    __builtin_amdgcn_s_setprio(1);
#pragma unroll
    for (int i = 0; i < 8; ++i)
#pragma unroll
      for (int j = 0; j < 4; ++j)
        acc[i][j] = __builtin_amdgcn_mfma_f32_16x16x32_bf16(
            af[i], bfr[j], acc[i][j], 0, 0, 0);
    __builtin_amdgcn_s_setprio(0);

    u16* tmp = rd; rd = nx; nx = st; st = tmp;
  }

  // ---- epilogue: C/D layout col=lane&15, row=(lane>>4)*4+i
  const int cr = lane & 15, rr0 = (lane >> 4) * 4;
  OutT* Cb = C + (size_t)bz * sC;
#pragma unroll
  for (int nj = 0; nj < 4; ++nj) {
    const int colg = blockN + wcol + nj * 16 + cr;
    const float bval = HAS_BIAS ? bias[colg] : 0.0f;
#pragma unroll
    for (int mi = 0; mi < 8; ++mi) {
      f32x4 v = acc[mi][nj];
      const int rowg = blockM + wrow + mi * 16 + rr0;
      if constexpr (MODE == 0) {
#pragma unroll
        for (int i = 0; i < 4; ++i)
          store_out(&Cb[(size_t)(rowg + i) * ldc + colg], v[i] * scale + bval);
      } else {
        if (colg < 2048) {
          u16* dst = (colg < 1024) ? (u16*)Cb : out2;
          const int c2 = colg & 1023;
#pragma unroll
          for (int i = 0; i < 4; ++i)
            dst[(size_t)(rowg + i) * 1024 + c2] = f2bf(v[i] + bval);
        } else {
          const int d  = colg - 2048;
          const int b  = rowg >> 11;
          const int t0 = rowg & 2047;
          u16 h0 = f2bf(v[0] + bval), h1 = f2bf(v[1] + bval);
          u16 h2 = f2bf(v[2] + bval), h3 = f2bf(v[3] + bval);
          uint2 u;
          u.x = (unsigned)h0 | ((unsigned)h1 << 16);
          u.y = (unsigned)h2 | ((unsigned)h3 << 16);
          *(uint2*)&out3[((size_t)b * 1024 + d) * 2048 + t0] = u;
        }
      }
    }
  }
}

// ---------------------------------------------------------------------------
// aux kernels
// ---------------------------------------------------------------------------
__global__ __launch_bounds__(256) void cvt_f32_bf16(
    const float* __restrict__ in, u16* __restrict__ out, int n4)
{
  int i = blockIdx.x * 256 + threadIdx.x;
  if (i >= n4) return;
  float4 v = ((const float4*)in)[i];
  uint2 u;
  u.x = (unsigned)f2bf(v.x) | ((unsigned)f2bf(v.y) << 16);
  u.y = (unsigned)f2bf(v.z) | ((unsigned)f2bf(v.w) << 16);
  ((uint2*)out)[i] = u;
}

__global__ __launch_bounds__(256) void transpose_cvt(
    const float* __restrict__ W, u16* __restrict__ Wt)
{
  __shared__ u16 tile[32][33];
  const int tx = threadIdx.x;
  const int ty = threadIdx.y;
  const int bx = blockIdx.x * 32;
  const int by = blockIdx.y * 32;
#pragma unroll
  for (int j = 0; j < 4; ++j) {
    int d = by + ty * 4 + j;
    tile[ty * 4 + j][tx] = f2bf(W[(size_t)d * DD + bx + tx]);
  }
  __syncthreads();
#pragma unroll
  for (int j = 0; j < 4; ++j) {
    int f = bx + ty * 4 + j;
    Wt[(size_t)f * DD + by + tx] = tile[tx][ty * 4 + j];
  }
}

__global__ __launch_bounds__(256) void concat_bias(
    const float* __restrict__ bq, const float* __restrict__ bk,
    const float* __restrict__ bv, float* __restrict__ out)
{
  int i = blockIdx.x * 256 + threadIdx.x;   // 3072 total
  const float* src = (i < 1024) ? bq : ((i < 2048) ? bk : bv);
  out[i] = src[i & 1023];
}

__global__ __launch_bounds__(256) void softmax_inplace(float* __restrict__ S)
{
  const int tid = threadIdx.x;
  float* rp = S + (size_t)blockIdx.x * SS;

  float4 v0 = ((const float4*)rp)[tid];
  float4 v1 = ((const float4*)rp)[tid + 256];

  float m = fmaxf(fmaxf(fmaxf(v0.x, v0.y), fmaxf(v0.z, v0.w)),
                  fmaxf(fmaxf(v1.x, v1.y), fmaxf(v1.z, v1.w)));
#pragma unroll
  for (int off = 32; off; off >>= 1) m = fmaxf(m, __shfl_xor(m, off));

  __shared__ float smax[4];
  __shared__ float ssum[4];
  const int wave = tid >> 6, lane = tid & 63;
  if (lane == 0) smax[wave] = m;
  __syncthreads();
  m = fmaxf(fmaxf(smax[0], smax[1]), fmaxf(smax[2], smax[3]));

  float e[8];
  e[0] = __expf(v0.x - m); e[1] = __expf(v0.y - m);
  e[2] = __expf(v0.z - m); e[3] = __expf(v0.w - m);
  e[4] = __expf(v1.x - m); e[5] = __expf(v1.y - m);
  e[6] = __expf(v1.z - m); e[7] = __expf(v1.w - m);
  float s = e[0] + e[1] + e[2] + e[3] + e[4] + e[5] + e[6] + e[7];
#pragma unroll
  for (int off = 32; off; off >>= 1) s += __shfl_xor(s, off);
  if (lane == 0) ssum[wave] = s;
  __syncthreads();
  float inv = 1.0f / (ssum[0] + ssum[1] + ssum[2] + ssum[3]);

  uint2 u0, u1;
  u0.x = (unsigned)f2bf(e[0] * inv) | ((unsigned)f2bf(e[1] * inv) << 16);
  u0.y = (unsigned)f2bf(e[2] * inv) | ((unsigned)f2bf(e[3] * inv) << 16);
  u1.x = (unsigned)f2bf(e[4] * inv) | ((unsigned)f2bf(e[5] * inv) << 16);
  u1.y = (unsigned)f2bf(e[6] * inv) | ((unsigned)f2bf(e[7] * inv) << 16);
  ((uint2*)rp)[tid]       = u0;
  ((uint2*)rp)[tid + 256] = u1;
}

// ---------------------------------------------------------------------------
extern "C" void kernel_launch(void* const* d_in, const int* in_sizes, int n_in,
                              void* d_out, int out_size, void* d_ws, size_t ws_size,
                              hipStream_t stream) {
  (void)in_sizes; (void)n_in; (void)out_size; (void)ws_size;
  const float* X  = (const float*)d_in[0];
  const float* Wq = (const float*)d_in[1];
  const float* bq = (const float*)d_in[2];
  const float* Wk = (const float*)d_in[3];
  const float* bk = (const float*)d_in[4];
  const float* Wv = (const float*)d_in[5];
  const float* bv = (const float*)d_in[6];
  const float* Wo = (const float*)d_in[7];
  const float* bo = (const float*)d_in[8];

  char* ws = (char*)d_ws;
  const size_t MBy = 1ull << 20;
  u16*   Xbf   = (u16*)(ws + 0);          // 16 MB [8192][1024]
  u16*   WtAll = (u16*)(ws + 16 * MBy);   //  6 MB [3072][1024] (Wq^T|Wk^T|Wv^T)
  u16*   Wto   = (u16*)(ws + 22 * MBy);   //  2 MB [1024][1024]
  u16*   Qb    = (u16*)(ws + 24 * MBy);   // 16 MB [8192][1024]
  u16*   Kb    = (u16*)(ws + 40 * MBy);   // 16 MB
  u16*   Vt    = (u16*)(ws + 56 * MBy);   // 16 MB [4][1024][2048]
  float* Sf    = (float*)(ws + 72 * MBy); // 64 MB [4][2048][2048]
  float* bqkv  = (float*)(ws + 72 * MBy); // aliases Sf (consumed before QK^T)
  u16*   Ctx   = (u16*)(ws + 136 * MBy);  // 16 MB [8192][1024]

  // 1. conversions + packing
  cvt_f32_bf16<<<dim3((BB * SS * DD / 4) / 256), 256, 0, stream>>>(X, Xbf, BB * SS * DD / 4);
  dim3 tb(32, 8);
  transpose_cvt<<<dim3(32, 32), tb, 0, stream>>>(Wq, WtAll);
  transpose_cvt<<<dim3(32, 32), tb, 0, stream>>>(Wk, WtAll + 1024 * 1024);
  transpose_cvt<<<dim3(32, 32), tb, 0, stream>>>(Wv, WtAll + 2 * 1024 * 1024);
  transpose_cvt<<<dim3(32, 32), tb, 0, stream>>>(Wo, Wto);
  concat_bias<<<dim3(12), 256, 0, stream>>>(bq, bk, bv, bqkv);

  // 2. merged QKV projection: [8192][3072]; V written transposed
  gemm8<u16, 1, true><<<dim3(12, 32, 1), 512, 0, stream>>>(
      Xbf, 0, DD * 2, WtAll, 0, DD * 2,
      Qb, 0, 0, bqkv, 1.0f, DD, Kb, Vt);

  // 3. scores = Q K^T / 8 (fp32)
  gemm8<float, 0, false><<<dim3(8, 8, BB), 512, 0, stream>>>(
      Qb, (size_t)SS * DD, DD * 2, Kb, (size_t)SS * DD, DD * 2,
      Sf, (size_t)SS * SS, SS, nullptr, 0.125f, DD, nullptr, nullptr);

  // 4. softmax rows (in-place fp32 -> bf16, lda becomes 4096 elems)
  softmax_inplace<<<dim3(BB * SS), 256, 0, stream>>>(Sf);

  // 5. ctx = P V  (P bf16 at 8192 B/row; B = Vt [1024][2048])
  gemm8<u16, 0, false><<<dim3(4, 8, BB), 512, 0, stream>>>(
      (const u16*)Sf, (size_t)SS * 2 * SS, 2 * SS * 2,
      Vt, (size_t)DD * SS, SS * 2,
      Ctx, (size_t)SS * DD, DD, nullptr, 1.0f, SS, nullptr, nullptr);

  // 6. out = ctx Wo^T + bo (fp32)
  gemm8<float, 0, true><<<dim3(4, 32, 1), 512, 0, stream>>>(
      Ctx, 0, DD * 2, Wto, 0, DD * 2,
      (float*)d_out, 0, DD, bo, 1.0f, DD, nullptr, nullptr);
}

// Round 3
// 223.953 us; speedup vs baseline: 1.2812x; 1.1172x over previous
//
#include <hip/hip_runtime.h>
#include <cstdint>
#include <cstddef>

typedef unsigned short u16;
typedef __attribute__((ext_vector_type(8))) short short8;
typedef __attribute__((ext_vector_type(4))) float f32x4;

#define BB 4
#define SS 2048
#define DD 1024

__device__ __forceinline__ u16 f2bf(float f) {
  union { float f; unsigned u; } x; x.f = f;
  unsigned r = x.u + 0x7FFFu + ((x.u >> 16) & 1u);
  return (u16)(r >> 16);
}

__device__ __forceinline__ void gld_lds16(const void* g, void* l) {
  __builtin_amdgcn_global_load_lds(
      (const __attribute__((address_space(1))) void*)g,
      (__attribute__((address_space(3))) void*)l, 16, 0, 0);
}

__device__ __forceinline__ void store_out(float* p, float v) { *p = v; }
__device__ __forceinline__ void store_out(u16* p, float v) { *p = f2bf(v); }

// ---------------------------------------------------------------------------
// 256xBN tile, BK=64, 8-wave GEMM. 8-phase-style schedule (T2+T3+T4+T5):
//  - ring of 4 A-slots (256x32) + 4 B-slots (BNx32) in LDS;
//  - per phase: ds_read frags | stage one slot-pair (prefetch dist 2 phases) |
//    vmcnt(NL) (never 0 mid-loop) | barrier | lgkmcnt(0)+sched_barrier |
//    setprio(1) MFMA burst setprio(0) | barrier.
//  - LDS swizzle: cbyte ^= ((row>>1)&3)<<4  (involution; 8 rows -> 8 slots
//    -> 2-way = free). Applied to BOTH pre-swizzled global stage source and
//    ds_read address; global_load_lds dest stays linear (rule 21).
// A: [M][K] bf16 (ldaB bytes/row), B: [N][K] bf16 (ldbB bytes/row).
// MODE 0: C[row][col] = acc*scale (+bias[col]).
// MODE 1 (QKV): cols 0-1023 -> C (Q), 1024-2047 -> out2 (K),
//               2048-3071 -> out3 = Vt[b][d][t] (all bf16, +bias).
// Grid: x=N/BN, y=M/256, z=batch; nwg % 8 == 0 (XCD swizzle bijective).
// K % 64 == 0, K >= 128.
// ---------------------------------------------------------------------------
template<typename OutT, int BN, int MODE, bool HAS_BIAS>
__global__ __launch_bounds__(512, 2) void gemm8p(
    const u16* __restrict__ A, size_t sA, int ldaB,
    const u16* __restrict__ B, size_t sB, int ldbB,
    OutT* __restrict__ C, size_t sC, int ldc,
    const float* __restrict__ bias, float scale, int K,
    u16* __restrict__ out2, u16* __restrict__ out3)
{
  constexpr int NFR   = BN / 64;    // n-frags per wave (4 or 2)
  constexpr int BSLOT = BN * 32;    // elems per B ring slot
  __shared__ u16 sm[32768 + 4 * BSLOT];   // 128 KB (BN=256) / 96 KB (BN=128)

  // ---- XCD-aware block swizzle
  const int gx = gridDim.x, gy = gridDim.y;
  const int nwg = gx * gy * gridDim.z;
  const int flat = blockIdx.x + gx * (blockIdx.y + gy * blockIdx.z);
  const int swz = (flat & 7) * (nwg >> 3) + (flat >> 3);
  const int bz  = swz / (gx * gy);
  const int rem = swz - bz * (gx * gy);
  const int by  = rem / gx;
  const int bx  = rem - by * gx;
  const int blockM = by * 256, blockN = bx * BN;

  const char* Abase = (const char*)(A + (size_t)bz * sA);
  const char* Bbase = (const char*)(B + (size_t)bz * sB);

  const int tid  = threadIdx.x;
  const int wave = tid >> 6, lane = tid & 63;
  const int wrow = (wave >> 2) * 128;
  const int wcol = (wave & 3) * (BN / 4);

  // ---- staging coords: thread -> (row, swizzled col-byte)
  const int sr  = tid >> 2;                                  // 0..127
  const int scb = ((tid & 3) * 16) ^ (((sr >> 1) & 3) << 4); // involution
  const char* gA0 = Abase + (size_t)(blockM + sr)       * ldaB + scb;
  const char* gA1 = Abase + (size_t)(blockM + sr + 128) * ldaB + scb;
  const char* gB0 = Bbase + (size_t)(blockN + sr)       * ldbB + scb;
  const char* gB1 = gB0;
  if constexpr (BN == 256) gB1 = Bbase + (size_t)(blockN + sr + 128) * ldbB + scb;
  const int ldsw = wave * 512;   // wave-uniform LDS dest (elems)

  // ---- precomputed swizzled frag read offsets (elems, slot-relative)
  const int r16 = lane & 15, q8 = (lane >> 4) * 8;
  int offA[8], offB[NFR];
#pragma unroll
  for (int mi = 0; mi < 8; ++mi) {
    const int row = wrow + mi * 16 + r16;
    offA[mi] = row * 32 + (q8 ^ (((row >> 1) & 3) << 3));
  }
#pragma unroll
  for (int nj = 0; nj < NFR; ++nj) {
    const int row = wcol + nj * 16 + r16;
    offB[nj] = row * 32 + (q8 ^ (((row >> 1) & 3) << 3));
  }

  // stage slot-pair (t,kh) into ring r: A 2 loads, B 2 (BN=256) or 1 load
  auto STAGE = [&](int r, int kb) {
    gld_lds16(gA0 + kb, sm + r * 8192 + ldsw);
    gld_lds16(gA1 + kb, sm + r * 8192 + 4096 + ldsw);
    gld_lds16(gB0 + kb, sm + 32768 + r * BSLOT + ldsw);
    if constexpr (BN == 256)
      gld_lds16(gB1 + kb, sm + 32768 + r * BSLOT + 4096 + ldsw);
  };

  f32x4 acc[8][NFR] = {};
  const int NT = K >> 6;

  // ---- prologue: stage (0,0)->ring0, (0,1)->ring1; gate ring0
  STAGE(0, 0);
  STAGE(1, 64);
  if constexpr (BN == 256) asm volatile("s_waitcnt vmcnt(4)" ::: "memory");
  else                     asm volatile("s_waitcnt vmcnt(3)" ::: "memory");
  __builtin_amdgcn_s_barrier();

  for (int t = 0; t < NT; ++t) {
#pragma unroll
    for (int kh = 0; kh < 2; ++kh) {
      const int ring = (2 * t + kh) & 3;
      const u16* As = sm + ring * 8192;
      const u16* Bs = sm + 32768 + ring * BSLOT;

      short8 af[8], bfv[NFR];
#pragma unroll
      for (int mi = 0; mi < 8; ++mi) af[mi] = *(const short8*)(As + offA[mi]);
#pragma unroll
      for (int nj = 0; nj < NFR; ++nj) bfv[nj] = *(const short8*)(Bs + offB[nj]);

      if (t + 1 < NT) {
        STAGE((ring + 2) & 3, (t + 1) * 128 + kh * 64);
        if constexpr (BN == 256) asm volatile("s_waitcnt vmcnt(4)" ::: "memory");
        else                     asm volatile("s_waitcnt vmcnt(3)" ::: "memory");
      } else {
        asm volatile("s_waitcnt vmcnt(0)" ::: "memory");
      }
      __builtin_amdgcn_s_barrier();
      asm volatile("s_waitcnt lgkmcnt(0)" ::: "memory");
      __builtin_amdgcn_sched_barrier(0);

      __builtin_amdgcn_s_setprio(1);
#pragma unroll
      for (int mi = 0; mi < 8; ++mi)
#pragma unroll
        for (int nj = 0; nj < NFR; ++nj)
          acc[mi][nj] = __builtin_amdgcn_mfma_f32_16x16x32_bf16(
              af[mi], bfv[nj], acc[mi][nj], 0, 0, 0);
      __builtin_amdgcn_s_setprio(0);
      __builtin_amdgcn_s_barrier();
    }
  }

  // ---- epilogue: C/D layout col=lane&15, row=(lane>>4)*4+i
  const int cr = lane & 15, rr0 = (lane >> 4) * 4;
  OutT* Cb = C + (size_t)bz * sC;
#pragma unroll
  for (int nj = 0; nj < NFR; ++nj) {
    const int colg = blockN + wcol + nj * 16 + cr;
    const float bval = HAS_BIAS ? bias[colg] : 0.0f;
#pragma unroll
    for (int mi = 0; mi < 8; ++mi) {
      f32x4 v = acc[mi][nj];
      const int rowg = blockM + wrow + mi * 16 + rr0;
      if constexpr (MODE == 0) {
#pragma unroll
        for (int i = 0; i < 4; ++i)
          store_out(&Cb[(size_t)(rowg + i) * ldc + colg], v[i] * scale + bval);
      } else {
        if (colg < 2048) {
          u16* dst = (colg < 1024) ? (u16*)Cb : out2;
          const int c2 = colg & 1023;
#pragma unroll
          for (int i = 0; i < 4; ++i)
            dst[(size_t)(rowg + i) * 1024 + c2] = f2bf(v[i] + bval);
        } else {
          const int d  = colg - 2048;
          const int b  = rowg >> 11;
          const int t0 = rowg & 2047;
          u16 h0 = f2bf(v[0] + bval), h1 = f2bf(v[1] + bval);
          u16 h2 = f2bf(v[2] + bval), h3 = f2bf(v[3] + bval);
          uint2 u;
          u.x = (unsigned)h0 | ((unsigned)h1 << 16);
          u.y = (unsigned)h2 | ((unsigned)h3 << 16);
          *(uint2*)&out3[((size_t)b * 1024 + d) * 2048 + t0] = u;
        }
      }
    }
  }
}

// ---------------------------------------------------------------------------
// aux kernels
// ---------------------------------------------------------------------------
__global__ __launch_bounds__(256) void cvt_f32_bf16(
    const float* __restrict__ in, u16* __restrict__ out, int n4)
{
  int i = blockIdx.x * 256 + threadIdx.x;
  if (i >= n4) return;
  float4 v = ((const float4*)in)[i];
  uint2 u;
  u.x = (unsigned)f2bf(v.x) | ((unsigned)f2bf(v.y) << 16);
  u.y = (unsigned)f2bf(v.z) | ((unsigned)f2bf(v.w) << 16);
  ((uint2*)out)[i] = u;
}

__global__ __launch_bounds__(256) void transpose_cvt(
    const float* __restrict__ W, u16* __restrict__ Wt)
{
  __shared__ u16 tile[32][33];
  const int tx = threadIdx.x;
  const int ty = threadIdx.y;
  const int bx = blockIdx.x * 32;
  const int by = blockIdx.y * 32;
#pragma unroll
  for (int j = 0; j < 4; ++j) {
    int d = by + ty * 4 + j;
    tile[ty * 4 + j][tx] = f2bf(W[(size_t)d * DD + bx + tx]);
  }
  __syncthreads();
#pragma unroll
  for (int j = 0; j < 4; ++j) {
    int f = bx + ty * 4 + j;
    Wt[(size_t)f * DD + by + tx] = tile[tx][ty * 4 + j];
  }
}

__global__ __launch_bounds__(256) void concat_bias(
    const float* __restrict__ bq, const float* __restrict__ bk,
    const float* __restrict__ bv, float* __restrict__ out)
{
  int i = blockIdx.x * 256 + threadIdx.x;   // 3072 total
  const float* src = (i < 1024) ? bq : ((i < 2048) ? bk : bv);
  out[i] = src[i & 1023];
}

__global__ __launch_bounds__(256) void softmax_inplace(float* __restrict__ S)
{
  const int tid = threadIdx.x;
  float* rp = S + (size_t)blockIdx.x * SS;

  float4 v0 = ((const float4*)rp)[tid];
  float4 v1 = ((const float4*)rp)[tid + 256];

  float m = fmaxf(fmaxf(fmaxf(v0.x, v0.y), fmaxf(v0.z, v0.w)),
                  fmaxf(fmaxf(v1.x, v1.y), fmaxf(v1.z, v1.w)));
#pragma unroll
  for (int off = 32; off; off >>= 1) m = fmaxf(m, __shfl_xor(m, off));

  __shared__ float smax[4];
  __shared__ float ssum[4];
  const int wave = tid >> 6, lane = tid & 63;
  if (lane == 0) smax[wave] = m;
  __syncthreads();
  m = fmaxf(fmaxf(smax[0], smax[1]), fmaxf(smax[2], smax[3]));

  float e[8];
  e[0] = __expf(v0.x - m); e[1] = __expf(v0.y - m);
  e[2] = __expf(v0.z - m); e[3] = __expf(v0.w - m);
  e[4] = __expf(v1.x - m); e[5] = __expf(v1.y - m);
  e[6] = __expf(v1.z - m); e[7] = __expf(v1.w - m);
  float s = e[0] + e[1] + e[2] + e[3] + e[4] + e[5] + e[6] + e[7];
#pragma unroll
  for (int off = 32; off; off >>= 1) s += __shfl_xor(s, off);
  if (lane == 0) ssum[wave] = s;
  __syncthreads();
  float inv = 1.0f / (ssum[0] + ssum[1] + ssum[2] + ssum[3]);

  uint2 u0, u1;
  u0.x = (unsigned)f2bf(e[0] * inv) | ((unsigned)f2bf(e[1] * inv) << 16);
  u0.y = (unsigned)f2bf(e[2] * inv) | ((unsigned)f2bf(e[3] * inv) << 16);
  u1.x = (unsigned)f2bf(e[4] * inv) | ((unsigned)f2bf(e[5] * inv) << 16);
  u1.y = (unsigned)f2bf(e[6] * inv) | ((unsigned)f2bf(e[7] * inv) << 16);
  ((uint2*)rp)[tid]       = u0;
  ((uint2*)rp)[tid + 256] = u1;
}

// ---------------------------------------------------------------------------
extern "C" void kernel_launch(void* const* d_in, const int* in_sizes, int n_in,
                              void* d_out, int out_size, void* d_ws, size_t ws_size,
                              hipStream_t stream) {
  (void)in_sizes; (void)n_in; (void)out_size; (void)ws_size;
  const float* X  = (const float*)d_in[0];
  const float* Wq = (const float*)d_in[1];
  const float* bq = (const float*)d_in[2];
  const float* Wk = (const float*)d_in[3];
  const float* bk = (const float*)d_in[4];
  const float* Wv = (const float*)d_in[5];
  const float* bv = (const float*)d_in[6];
  const float* Wo = (const float*)d_in[7];
  const float* bo = (const float*)d_in[8];

  char* ws = (char*)d_ws;
  const size_t MBy = 1ull << 20;
  u16*   Xbf   = (u16*)(ws + 0);          // 16 MB [8192][1024]
  u16*   WtAll = (u16*)(ws + 16 * MBy);   //  6 MB [3072][1024]
  u16*   Wto   = (u16*)(ws + 22 * MBy);   //  2 MB [1024][1024]
  u16*   Qb    = (u16*)(ws + 24 * MBy);   // 16 MB [8192][1024]
  u16*   Kb    = (u16*)(ws + 40 * MBy);   // 16 MB
  u16*   Vt    = (u16*)(ws + 56 * MBy);   // 16 MB [4][1024][2048]
  float* Sf    = (float*)(ws + 72 * MBy); // 64 MB [4][2048][2048]
  float* bqkv  = (float*)(ws + 72 * MBy); // aliases Sf (consumed before QK^T)
  u16*   Ctx   = (u16*)(ws + 136 * MBy);  // 16 MB [8192][1024]

  // 1. conversions + packing
  cvt_f32_bf16<<<dim3((BB * SS * DD / 4) / 256), 256, 0, stream>>>(X, Xbf, BB * SS * DD / 4);
  dim3 tb(32, 8);
  transpose_cvt<<<dim3(32, 32), tb, 0, stream>>>(Wq, WtAll);
  transpose_cvt<<<dim3(32, 32), tb, 0, stream>>>(Wk, WtAll + 1024 * 1024);
  transpose_cvt<<<dim3(32, 32), tb, 0, stream>>>(Wv, WtAll + 2 * 1024 * 1024);
  transpose_cvt<<<dim3(32, 32), tb, 0, stream>>>(Wo, Wto);
  concat_bias<<<dim3(12), 256, 0, stream>>>(bq, bk, bv, bqkv);

  // 2. merged QKV projection: [8192][3072]; V written transposed (768 blocks)
  gemm8p<u16, 128, 1, true><<<dim3(24, 32, 1), 512, 0, stream>>>(
      Xbf, 0, DD * 2, WtAll, 0, DD * 2,
      Qb, 0, 0, bqkv, 1.0f, DD, Kb, Vt);

  // 3. scores = Q K^T / 8 (fp32, 256 blocks)
  gemm8p<float, 256, 0, false><<<dim3(8, 8, BB), 512, 0, stream>>>(
      Qb, (size_t)SS * DD, DD * 2, Kb, (size_t)SS * DD, DD * 2,
      Sf, (size_t)SS * SS, SS, nullptr, 0.125f, DD, nullptr, nullptr);

  // 4. softmax rows (in-place fp32 -> bf16)
  softmax_inplace<<<dim3(BB * SS), 256, 0, stream>>>(Sf);

  // 5. ctx = P V  (P bf16 rows of 8192 B; B = Vt [1024][2048]; 256 blocks)
  gemm8p<u16, 128, 0, false><<<dim3(8, 8, BB), 512, 0, stream>>>(
      (const u16*)Sf, (size_t)SS * 2 * SS, 2 * SS * 2,
      Vt, (size_t)DD * SS, SS * 2,
      Ctx, (size_t)SS * DD, DD, nullptr, 1.0f, SS, nullptr, nullptr);

  // 6. out = ctx Wo^T + bo (fp32, 256 blocks)
  gemm8p<float, 128, 0, true><<<dim3(8, 32, 1), 512, 0, stream>>>(
      Ctx, 0, DD * 2, Wto, 0, DD * 2,
      (float*)d_out, 0, DD, bo, 1.0f, DD, nullptr, nullptr);
}

// Round 4
// 216.585 us; speedup vs baseline: 1.3248x; 1.0340x over previous
//
#include <hip/hip_runtime.h>
#include <cstdint>
#include <cstddef>

typedef unsigned short u16;
typedef __attribute__((ext_vector_type(8))) short short8;
typedef __attribute__((ext_vector_type(4))) float f32x4;

#define BB 4
#define SS 2048
#define DD 1024

__device__ __forceinline__ u16 f2bf(float f) {
  union { float f; unsigned u; } x; x.f = f;
  unsigned r = x.u + 0x7FFFu + ((x.u >> 16) & 1u);
  return (u16)(r >> 16);
}

__device__ __forceinline__ void gld_lds16(const void* g, void* l) {
  __builtin_amdgcn_global_load_lds(
      (const __attribute__((address_space(1))) void*)g,
      (__attribute__((address_space(3))) void*)l, 16, 0, 0);
}

__device__ __forceinline__ void store_out(float* p, float v) { *p = v; }
__device__ __forceinline__ void store_out(u16* p, float v) { *p = f2bf(v); }

// ---------------------------------------------------------------------------
// BMx256 tile, 8 waves (2M x 4N), per-wave tile (BM/2)x64.
// 4-slot LDS ring of (BMx32 A + 256x32 B); prefetch distance 3.
// Phase p: [ds_read slot p] [vmcnt(L) counted] [s_barrier] [STAGE slot p+3]
//          [setprio(1) MFMA-cluster setprio(0)] — ONE barrier per phase,
//          stage issued 3 phases ahead => ~2 phases of memory-latency cover.
// Safety: reads(p) gated by phase p-1's vmcnt+barrier; STAGE target
// (p+3)&3=(p-1)&3 whose reads completed before barrier(p) (MFMA(p-1)
// consumed them; sched_barrier(0) pins clusters). vmcnt never 0 mid-loop.
// LDS swizzle (both-sides involution): cbyte ^= ((row>>1)&3)<<4.
// A: [M][K] bf16 (ldaB bytes/row), B: [N][K] bf16 (ldbB bytes/row).
// MODE 0: C[row][col] = acc*scale (+bias[col]).
// MODE 1 (QKV, BM=256): cols 0-1023 -> C (Q), 1024-2047 -> out2 (K),
//                       2048-3071 -> out3 = Vt[b][d][t] (bf16, +bias).
// Grid: x=N/256, y=M/BM, z=batch; nwg % 8 == 0. K % 64 == 0, K >= 192.
// ---------------------------------------------------------------------------
template<typename OutT, int BM, int MODE, bool HAS_BIAS>
__global__ __launch_bounds__(512, 2) void gemm8p(
    const u16* __restrict__ A, size_t sA, int ldaB,
    const u16* __restrict__ B, size_t sB, int ldbB,
    OutT* __restrict__ C, size_t sC, int ldc,
    const float* __restrict__ bias, float scale, int K,
    u16* __restrict__ out2, u16* __restrict__ out3)
{
  constexpr int MF    = BM / 32;        // m-frags per wave (8 or 4)
  constexpr int ASLOT = BM * 32;        // elems per A ring slot
  constexpr int ASETS = BM / 128;       // 8KB load-sets per A slot (2 or 1)
  constexpr int L     = ASETS + 2;      // global_load_lds per STAGE
  __shared__ u16 sm[4 * ASLOT + 4 * 8192];   // 128 KB / 96 KB

  // ---- XCD-aware block swizzle (bijective: nwg % 8 == 0)
  const int gx = gridDim.x, gy = gridDim.y;
  const int nwg = gx * gy * gridDim.z;
  const int flat = blockIdx.x + gx * (blockIdx.y + gy * blockIdx.z);
  const int swz = (flat & 7) * (nwg >> 3) + (flat >> 3);
  const int bz  = swz / (gx * gy);
  const int rem = swz - bz * (gx * gy);
  const int by  = rem / gx;
  const int bx  = rem - by * gx;
  const int blockM = by * BM, blockN = bx * 256;

  const char* Abase = (const char*)(A + (size_t)bz * sA);
  const char* Bbase = (const char*)(B + (size_t)bz * sB);

  const int tid  = threadIdx.x;
  const int wave = tid >> 6, lane = tid & 63;
  const int wrow = (wave >> 2) * (BM / 2);
  const int wcol = (wave & 3) * 64;

  // ---- staging coords: thread -> (row 0..127, swizzled col-byte)
  const int sr  = tid >> 2;
  const int scb = ((tid & 3) * 16) ^ (((sr >> 1) & 3) << 4);
  const char* gA0 = Abase + (size_t)(blockM + sr) * ldaB + scb;
  const char* gA1 = (ASETS == 2) ? Abase + (size_t)(blockM + sr + 128) * ldaB + scb
                                 : nullptr;
  const char* gB0 = Bbase + (size_t)(blockN + sr)       * ldbB + scb;
  const char* gB1 = Bbase + (size_t)(blockN + sr + 128) * ldbB + scb;
  const int ldsw = wave * 512;   // wave-uniform LDS dest base (elems)

  // stage one BK=32 slot of A+B into ring slot r; advances k by 64 bytes
  auto STAGE = [&](int r) {
    gld_lds16(gA0, sm + r * ASLOT + ldsw);
    if constexpr (ASETS == 2) gld_lds16(gA1, sm + r * ASLOT + 4096 + ldsw);
    gld_lds16(gB0, sm + 4 * ASLOT + r * 8192 + ldsw);
    gld_lds16(gB1, sm + 4 * ASLOT + r * 8192 + 4096 + ldsw);
    gA0 += 64; gB0 += 64; gB1 += 64;
    if constexpr (ASETS == 2) gA1 += 64;
  };

  // ---- precomputed swizzled frag read offsets (elems, slot-relative)
  const int r16 = lane & 15, q8 = (lane >> 4) * 8;
  int offA[MF], offB[4];
#pragma unroll
  for (int mi = 0; mi < MF; ++mi) {
    const int row = wrow + mi * 16 + r16;
    offA[mi] = row * 32 + (q8 ^ (((row >> 1) & 3) << 3));
  }
#pragma unroll
  for (int nj = 0; nj < 4; ++nj) {
    const int row = wcol + nj * 16 + r16;
    offB[nj] = row * 32 + (q8 ^ (((row >> 1) & 3) << 3));
  }

  f32x4 acc[MF][4] = {};
  const int NP = K >> 5;   // phases (BK=32 each)

  // ---- prologue: stage slots for phases 0,1,2; gate slot 0
  STAGE(0); STAGE(1); STAGE(2);
  asm volatile("s_waitcnt vmcnt(%0)" :: "i"(2 * L) : "memory");
  __builtin_amdgcn_s_barrier();
  __builtin_amdgcn_sched_barrier(0);

  for (int p = 0; p < NP; ++p) {
    const int ring = p & 3;
    const u16* As = sm + ring * ASLOT;
    const u16* Bs = sm + 4 * ASLOT + ring * 8192;

    short8 bfv[4], af[MF];
#pragma unroll
    for (int nj = 0; nj < 4; ++nj) bfv[nj] = *(const short8*)(Bs + offB[nj]);
#pragma unroll
    for (int mi = 0; mi < MF; ++mi) af[mi] = *(const short8*)(As + offA[mi]);

    // counted wait: ensure slot p+1 (issued at p-2) has landed; keep the
    // newest stage (slot p+2) in flight. Never drain mid-loop.
    if (p < NP - 2)       asm volatile("s_waitcnt vmcnt(%0)" :: "i"(L) : "memory");
    else if (p == NP - 2) asm volatile("s_waitcnt vmcnt(0)" ::: "memory");
    __builtin_amdgcn_s_barrier();
    __builtin_amdgcn_sched_barrier(0);

    if (p + 3 < NP) STAGE((p + 3) & 3);

    __builtin_amdgcn_s_setprio(1);
#pragma unroll
    for (int mi = 0; mi < MF; ++mi)
#pragma unroll
      for (int nj = 0; nj < 4; ++nj)
        acc[mi][nj] = __builtin_amdgcn_mfma_f32_16x16x32_bf16(
            af[mi], bfv[nj], acc[mi][nj], 0, 0, 0);
    __builtin_amdgcn_s_setprio(0);
    __builtin_amdgcn_sched_barrier(0);
  }

  // ---- epilogue: C/D layout col=lane&15, row=(lane>>4)*4+i
  const int cr = lane & 15, rr0 = (lane >> 4) * 4;
  OutT* Cb = C + (size_t)bz * sC;
#pragma unroll
  for (int nj = 0; nj < 4; ++nj) {
    const int colg = blockN + wcol + nj * 16 + cr;
    const float bval = HAS_BIAS ? bias[colg] : 0.0f;
#pragma unroll
    for (int mi = 0; mi < MF; ++mi) {
      f32x4 v = acc[mi][nj];
      const int rowg = blockM + wrow + mi * 16 + rr0;
      if constexpr (MODE == 0) {
#pragma unroll
        for (int i = 0; i < 4; ++i)
          store_out(&Cb[(size_t)(rowg + i) * ldc + colg], v[i] * scale + bval);
      } else {
        if (colg < 2048) {
          u16* dst = (colg < 1024) ? (u16*)Cb : out2;
          const int c2 = colg & 1023;
#pragma unroll
          for (int i = 0; i < 4; ++i)
            dst[(size_t)(rowg + i) * 1024 + c2] = f2bf(v[i] + bval);
        } else {
          const int d  = colg - 2048;
          const int b  = rowg >> 11;
          const int t0 = rowg & 2047;
          u16 h0 = f2bf(v[0] + bval), h1 = f2bf(v[1] + bval);
          u16 h2 = f2bf(v[2] + bval), h3 = f2bf(v[3] + bval);
          uint2 u;
          u.x = (unsigned)h0 | ((unsigned)h1 << 16);
          u.y = (unsigned)h2 | ((unsigned)h3 << 16);
          *(uint2*)&out3[((size_t)b * 1024 + d) * 2048 + t0] = u;
        }
      }
    }
  }
}

// ---------------------------------------------------------------------------
// aux kernels
// ---------------------------------------------------------------------------
__global__ __launch_bounds__(256) void cvt_f32_bf16(
    const float* __restrict__ in, u16* __restrict__ out, int n4)
{
  int i = blockIdx.x * 256 + threadIdx.x;
  if (i >= n4) return;
  float4 v = ((const float4*)in)[i];
  uint2 u;
  u.x = (unsigned)f2bf(v.x) | ((unsigned)f2bf(v.y) << 16);
  u.y = (unsigned)f2bf(v.z) | ((unsigned)f2bf(v.w) << 16);
  ((uint2*)out)[i] = u;
}

__global__ __launch_bounds__(256) void transpose_cvt(
    const float* __restrict__ W, u16* __restrict__ Wt)
{
  __shared__ u16 tile[32][33];
  const int tx = threadIdx.x;
  const int ty = threadIdx.y;
  const int bx = blockIdx.x * 32;
  const int by = blockIdx.y * 32;
#pragma unroll
  for (int j = 0; j < 4; ++j) {
    int d = by + ty * 4 + j;
    tile[ty * 4 + j][tx] = f2bf(W[(size_t)d * DD + bx + tx]);
  }
  __syncthreads();
#pragma unroll
  for (int j = 0; j < 4; ++j) {
    int f = bx + ty * 4 + j;
    Wt[(size_t)f * DD + by + tx] = tile[tx][ty * 4 + j];
  }
}

__global__ __launch_bounds__(256) void concat_bias(
    const float* __restrict__ bq, const float* __restrict__ bk,
    const float* __restrict__ bv, float* __restrict__ out)
{
  int i = blockIdx.x * 256 + threadIdx.x;   // 3072 total
  const float* src = (i < 1024) ? bq : ((i < 2048) ? bk : bv);
  out[i] = src[i & 1023];
}

__global__ __launch_bounds__(256) void softmax_inplace(float* __restrict__ S)
{
  const int tid = threadIdx.x;
  float* rp = S + (size_t)blockIdx.x * SS;

  float4 v0 = ((const float4*)rp)[tid];
  float4 v1 = ((const float4*)rp)[tid + 256];

  float m = fmaxf(fmaxf(fmaxf(v0.x, v0.y), fmaxf(v0.z, v0.w)),
                  fmaxf(fmaxf(v1.x, v1.y), fmaxf(v1.z, v1.w)));
#pragma unroll
  for (int off = 32; off; off >>= 1) m = fmaxf(m, __shfl_xor(m, off));

  __shared__ float smax[4];
  __shared__ float ssum[4];
  const int wave = tid >> 6, lane = tid & 63;
  if (lane == 0) smax[wave] = m;
  __syncthreads();
  m = fmaxf(fmaxf(smax[0], smax[1]), fmaxf(smax[2], smax[3]));

  float e[8];
  e[0] = __expf(v0.x - m); e[1] = __expf(v0.y - m);
  e[2] = __expf(v0.z - m); e[3] = __expf(v0.w - m);
  e[4] = __expf(v1.x - m); e[5] = __expf(v1.y - m);
  e[6] = __expf(v1.z - m); e[7] = __expf(v1.w - m);
  float s = e[0] + e[1] + e[2] + e[3] + e[4] + e[5] + e[6] + e[7];
#pragma unroll
  for (int off = 32; off; off >>= 1) s += __shfl_xor(s, off);
  if (lane == 0) ssum[wave] = s;
  __syncthreads();
  float inv = 1.0f / (ssum[0] + ssum[1] + ssum[2] + ssum[3]);

  uint2 u0, u1;
  u0.x = (unsigned)f2bf(e[0] * inv) | ((unsigned)f2bf(e[1] * inv) << 16);
  u0.y = (unsigned)f2bf(e[2] * inv) | ((unsigned)f2bf(e[3] * inv) << 16);
  u1.x = (unsigned)f2bf(e[4] * inv) | ((unsigned)f2bf(e[5] * inv) << 16);
  u1.y = (unsigned)f2bf(e[6] * inv) | ((unsigned)f2bf(e[7] * inv) << 16);
  ((uint2*)rp)[tid]       = u0;
  ((uint2*)rp)[tid + 256] = u1;
}

// ---------------------------------------------------------------------------
extern "C" void kernel_launch(void* const* d_in, const int* in_sizes, int n_in,
                              void* d_out, int out_size, void* d_ws, size_t ws_size,
                              hipStream_t stream) {
  (void)in_sizes; (void)n_in; (void)out_size; (void)ws_size;
  const float* X  = (const float*)d_in[0];
  const float* Wq = (const float*)d_in[1];
  const float* bq = (const float*)d_in[2];
  const float* Wk = (const float*)d_in[3];
  const float* bk = (const float*)d_in[4];
  const float* Wv = (const float*)d_in[5];
  const float* bv = (const float*)d_in[6];
  const float* Wo = (const float*)d_in[7];
  const float* bo = (const float*)d_in[8];

  char* ws = (char*)d_ws;
  const size_t MBy = 1ull << 20;
  u16*   Xbf   = (u16*)(ws + 0);          // 16 MB [8192][1024]
  u16*   WtAll = (u16*)(ws + 16 * MBy);   //  6 MB [3072][1024]
  u16*   Wto   = (u16*)(ws + 22 * MBy);   //  2 MB [1024][1024]
  u16*   Qb    = (u16*)(ws + 24 * MBy);   // 16 MB [8192][1024]
  u16*   Kb    = (u16*)(ws + 40 * MBy);   // 16 MB
  u16*   Vt    = (u16*)(ws + 56 * MBy);   // 16 MB [4][1024][2048]
  float* Sf    = (float*)(ws + 72 * MBy); // 64 MB [4][2048][2048]
  float* bqkv  = (float*)(ws + 72 * MBy); // aliases Sf (consumed before QK^T)
  u16*   Ctx   = (u16*)(ws + 136 * MBy);  // 16 MB [8192][1024]

  // 1. conversions + packing
  cvt_f32_bf16<<<dim3((BB * SS * DD / 4) / 256), 256, 0, stream>>>(X, Xbf, BB * SS * DD / 4);
  dim3 tb(32, 8);
  transpose_cvt<<<dim3(32, 32), tb, 0, stream>>>(Wq, WtAll);
  transpose_cvt<<<dim3(32, 32), tb, 0, stream>>>(Wk, WtAll + 1024 * 1024);
  transpose_cvt<<<dim3(32, 32), tb, 0, stream>>>(Wv, WtAll + 2 * 1024 * 1024);
  transpose_cvt<<<dim3(32, 32), tb, 0, stream>>>(Wo, Wto);
  concat_bias<<<dim3(12), 256, 0, stream>>>(bq, bk, bv, bqkv);

  // 2. merged QKV projection: [8192][3072]; V written transposed (384 blocks)
  gemm8p<u16, 256, 1, true><<<dim3(12, 32, 1), 512, 0, stream>>>(
      Xbf, 0, DD * 2, WtAll, 0, DD * 2,
      Qb, 0, 0, bqkv, 1.0f, DD, Kb, Vt);

  // 3. scores = Q K^T / 8 (fp32, 256 blocks)
  gemm8p<float, 256, 0, false><<<dim3(8, 8, BB), 512, 0, stream>>>(
      Qb, (size_t)SS * DD, DD * 2, Kb, (size_t)SS * DD, DD * 2,
      Sf, (size_t)SS * SS, SS, nullptr, 0.125f, DD, nullptr, nullptr);

  // 4. softmax rows (in-place fp32 -> bf16)
  softmax_inplace<<<dim3(BB * SS), 256, 0, stream>>>(Sf);

  // 5. ctx = P V  (P bf16 rows of 8192 B; B = Vt [1024][2048]; 256 blocks)
  gemm8p<u16, 128, 0, false><<<dim3(4, 16, BB), 512, 0, stream>>>(
      (const u16*)Sf, (size_t)SS * 2 * SS, 2 * SS * 2,
      Vt, (size_t)DD * SS, SS * 2,
      Ctx, (size_t)SS * DD, DD, nullptr, 1.0f, SS, nullptr, nullptr);

  // 6. out = ctx Wo^T + bo (fp32, 256 blocks)
  gemm8p<float, 128, 0, true><<<dim3(4, 64, 1), 512, 0, stream>>>(
      Ctx, 0, DD * 2, Wto, 0, DD * 2,
      (float*)d_out, 0, DD, bo, 1.0f, DD, nullptr, nullptr);
}